// Round 3
// baseline (428.502 us; speedup 1.0000x reference)
//
#include <hip/hip_runtime.h>
#include <stdint.h>

#define NPTS  8192
#define NB    4
#define KNN   20
#define NROWS (NB * NPTS)        // 32768
#define MTOTF 655360.0f          // NROWS * KNN
#define WPB   8                  // waves per block; all waves share the same 64 rows
#define BLK   (WPB * 64)         // 512 threads
#define SLICE (NPTS / WPB)       // 1024 candidates per wave (fallback kernel)
#define HALF  (NPTS / 2)         // 4096 candidates per split block
#define SLICE2 (HALF / WPB)      // 512 candidates per wave (hot/split kernels)
#define LSTR  (KNN + 1)          // stride-21: odd stride -> conflict-free ladder
#define CAP   12                 // fallback push-buffer slots
#define CW    14                 // hot-section slots per (wave,lane)
#define WARM  32                 // private warm-up candidates per wave
#define NPH   15                 // (SLICE2 - WARM) / 32 scan phases
#define NEG_INF -3.0e38f
#define SENTU 0x7fbfffffu        // NaN bit pattern: cannot be produced by fma of finite inputs

__device__ __forceinline__ float med3f(float a, float b, float c) {
    return __builtin_amdgcn_fmed3f(a, b, c);
}

// Monotone float<->uint encoding (used by the fallback kernel's atomicMax threshold).
__device__ __forceinline__ unsigned enc_f(float f) {
    unsigned u = __float_as_uint(f);
    return (u & 0x80000000u) ? ~u : (u | 0x80000000u);
}
__device__ __forceinline__ float dec_f(unsigned u) {
    return __uint_as_float((u & 0x80000000u) ? (u & 0x7fffffffu) : ~u);
}

// Insert t into descending top-KNN list (arr[0] = largest t = nearest point).
// Dropping a value off the bottom is always exact: 20 larger witnesses exist.
__device__ __forceinline__ void insert_t(float arr[KNN], float t) {
#pragma unroll
    for (int j = KNN - 1; j > 0; --j) arr[j] = med3f(t, arr[j - 1], arr[j]);
    arr[0] = fmaxf(arr[0], t);
}

// ---- fallback (round-1) flush: fixed CAP, padded ----
__device__ __forceinline__ void flush_buf(float arr[KNN], int& cnt,
    const float* bufw, int lane, unsigned* threshS) {
#pragma unroll
    for (int s = 0; s < CAP; ++s) {
        const float v = bufw[s * 64 + lane];
        insert_t(arr, (s < cnt) ? v : NEG_INF);
    }
    cnt = 0;
    atomicMax(&threshS[lane], enc_f(arr[KNN - 1]));
}

// ---- hot kernel: drain all 8 sections of every row into the LDS ladder ----
// Single drainer wave per call; sections are single-writer, sentinel-terminated.
// cur stops AT a sentinel (hole) and resumes next drain -> no value skipped.
__device__ __forceinline__ void drain_rows(
    const float* hotS, float* ladS, float* threshS, int* curS, int lane)
{
    float lad[KNN];
#pragma unroll
    for (int k = 0; k < KNN; ++k) lad[k] = ladS[lane * LSTR + k];
    for (int w = 0; w < WPB; ++w) {
        int cur = curS[w * 64 + lane];
        while (true) {
            bool act = cur < CW;
            float v = NEG_INF;
            if (act) v = hotS[(w * CW + cur) * 64 + lane];
            act = act && (__float_as_uint(v) != SENTU);
            if (!__any(act)) break;
            if (act) { insert_t(lad, v); ++cur; }
        }
        curS[w * 64 + lane] = cur;
    }
#pragma unroll
    for (int k = 0; k < KNN; ++k) ladS[lane * LSTR + k] = lad[k];
    threshS[lane] = lad[KNN - 1];
}

// Merge a private register ladder into the shared LDS ladder (dump / cleanup).
__device__ __forceinline__ void merge_arr_to_lad(
    float* ladS, float* threshS, const float arr[KNN], int lane)
{
    float lad[KNN];
#pragma unroll
    for (int k = 0; k < KNN; ++k) lad[k] = ladS[lane * LSTR + k];
#pragma unroll
    for (int k = 0; k < KNN; ++k) insert_t(lad, arr[k]);
#pragma unroll
    for (int k = 0; k < KNN; ++k) ladS[lane * LSTR + k] = lad[k];
    threshS[lane] = lad[KNN - 1];
}

// Shared tail: caller holds the merged descending-t list for row `row`.
// t = p.q - |q|^2/2, d2 = |p|^2 - 2t  (arr[0] = largest t = nearest).
__device__ __forceinline__ void finalize_row(
    float arr[KNN], float px, float py, float pz, int row, int lane,
    float* __restrict__ kmaxA, float* __restrict__ kminA, float* __restrict__ acc)
{
    const float pn2 = px * px + py * py + pz * pz;
    float sum = 0.f, sum2 = 0.f, dmin = 0.f, dmax = 0.f;
#pragma unroll
    for (int k = 0; k < KNN; ++k) {
        float d2 = fmaxf(fmaf(-2.f, arr[k], pn2), 0.f);
        float d = sqrtf(d2);
        sum += d; sum2 += d2;
        if (k == 0) dmin = d;
        dmax = d;
    }
    kmaxA[row] = dmax;
    kminA[row] = dmin;
#pragma unroll
    for (int o = 32; o; o >>= 1) {
        sum  += __shfl_down(sum,  o, 64);
        sum2 += __shfl_down(sum2, o, 64);
    }
    if (lane == 0) { atomicAdd(acc, sum); atomicAdd(acc + 1, sum2); }
}

// Prep: tile4[b*NPTS+m] = (qx, qy, qz, -|q|^2/2); zero the stats accumulator.
__global__ __launch_bounds__(256) void prep_kernel(
    const float* __restrict__ x, float4* __restrict__ tile4, float* __restrict__ acc)
{
    const int i = blockIdx.x * 256 + threadIdx.x;    // 0..32767
    const int b = i >> 13;
    const int m = i & (NPTS - 1);
    const float* xb = x + b * 3 * NPTS;
    const float qx = xb[m], qy = xb[NPTS + m], qz = xb[2 * NPTS + m];
    tile4[i] = make_float4(qx, qy, qz, -0.5f * (qx * qx + qy * qy + qz * qz));
    if (i < 2) acc[i] = 0.f;
}

// K1 (main): ONE shared top-20 ladder per row (LDS), survivors pooled.
// Scan waves: 3 fma + threshold test + rare 2-op push into a private
// per-(wave,lane) section. Rotating drainer wave folds sections into the
// ladder once per 32-candidate phase and republishes the threshold.
// Threshold converges as 20/m_block -> ~70 survivors/row (vs ~1000 with
// per-stream ladders). Ladder work paid ONCE per row, not 16x.
__global__ __launch_bounds__(BLK, 8) void knn_hot_kernel(
    const float* __restrict__ x, const float4* __restrict__ tile4,
    float* __restrict__ part)
{
    __shared__ float    hotS[WPB * CW * 64];   // 28672 B survivor sections
    __shared__ float    ladS[64 * LSTR];       // 5376 B  row ladders (stride 21)
    __shared__ float    threshS[64];
    __shared__ int      curS[WPB * 64];        // drain cursors
    __shared__ unsigned dirtyS;

    const int tid  = threadIdx.x;
    const int lane = tid & 63;
    const int wave = __builtin_amdgcn_readfirstlane(tid >> 6);
    const int rb   = blockIdx.x >> 1;        // row-group 0..511
    const int half = blockIdx.x & 1;         // candidate half
    const int rowBase = rb * 64;
    const int row  = rowBase + lane;
    const int b    = rowBase >> 13;
    const int n    = row & (NPTS - 1);
    const float* xb = x + b * 3 * NPTS;
    const float px = xb[n];
    const float py = xb[NPTS + n];
    const float pz = xb[2 * NPTS + n];

    // init: sentinels, cursors, dirty flag (covered by dump-round barriers)
    for (int i = tid; i < WPB * CW * 64; i += BLK) ((unsigned*)hotS)[i] = SENTU;
    for (int i = tid; i < WPB * 64; i += BLK) curS[i] = 0;
    if (tid == 0) dirtyS = 0u;

    float arr[KNN];
#pragma unroll
    for (int j = 0; j < KNN; ++j) arr[j] = NEG_INF;

    const float4* __restrict__ tp = tile4 + b * NPTS + half * HALF + wave * SLICE2;

    // Warm-up: private register ladder over first 32 candidates (no LDS).
#pragma unroll 4
    for (int i = 0; i < WARM; ++i) {
        const float4 q = tp[i];               // wave-uniform -> scalar load
        insert_t(arr, fmaf(q.x, px, fmaf(q.y, py, fmaf(q.z, pz, q.w))));
    }

    // Serialized dump rounds: ladder = exact top-20 of 8x32 = 256 candidates.
    for (int w = 0; w < WPB; ++w) {
        __syncthreads();
        if (wave == w) {
            if (w == 0) {
#pragma unroll
                for (int k = 0; k < KNN; ++k) ladS[lane * LSTR + k] = arr[k];
                threshS[lane] = arr[KNN - 1];
            } else {
                merge_arr_to_lad(ladS, threshS, arr, lane);
            }
        }
    }
    __syncthreads();

#pragma unroll
    for (int j = 0; j < KNN; ++j) arr[j] = NEG_INF;   // arr -> overflow backstop

    float* secp = &hotS[(wave * CW) * 64 + lane];
    int cnt = 0;

    for (int p = 0; p < NPH; ++p) {
        const float th = threshS[lane];       // stale by <=1 phase = conservative
        if (wave == (p & 7))
            drain_rows(hotS, ladS, threshS, curS, lane);
        const float4* tq = tp + WARM + p * 32;
#pragma unroll 4
        for (int i = 0; i < 32; ++i) {
            const float4 q = tq[i];           // wave-uniform -> scalar load
            const float t = fmaf(q.x, px, fmaf(q.y, py, fmaf(q.z, pz, q.w)));
            if (t > th) {
                if (cnt < CW) { secp[cnt * 64] = t; ++cnt; }
                else { insert_t(arr, t); atomicOr(&dirtyS, 1u); }  // ~never
            }
        }
        __syncthreads();
    }

    // final drain of the last phase's pushes
    if (wave == 7) drain_rows(hotS, ladS, threshS, curS, lane);
    __syncthreads();

    // cleanup of overflow residue (block-uniform branch; ~always skipped)
    if (dirtyS) {
        for (int w = 0; w < WPB; ++w) {
            __syncthreads();
            if (wave == w && __any(arr[0] != NEG_INF))
                merge_arr_to_lad(ladS, threshS, arr, lane);
        }
    }
    __syncthreads();

    // write sorted partial list: part[(row*2+half)*20 .. +19]
    if (wave == 0) {
        float o[KNN];
#pragma unroll
        for (int k = 0; k < KNN; ++k) o[k] = ladS[lane * LSTR + k];
        float4* dst = (float4*)(part + (row * 2 + half) * KNN);
#pragma unroll
        for (int k = 0; k < KNN; k += 4)
            dst[k >> 2] = make_float4(o[k], o[k + 1], o[k + 2], o[k + 3]);
    }
}

// K1b: merge the two sorted partial lists per row, then finalize
// (kmax/kmin + BN-stat atomics). One thread per row.
__global__ __launch_bounds__(256) void merge_kernel(
    const float* __restrict__ x, const float* __restrict__ part,
    float* __restrict__ kmaxA, float* __restrict__ kminA, float* __restrict__ acc)
{
    const int r = blockIdx.x * 256 + threadIdx.x;   // 0..32767
    const int lane = threadIdx.x & 63;
    const int b = r >> 13;
    const int n = r & (NPTS - 1);
    const float* xb = x + b * 3 * NPTS;
    const float px = xb[n];
    const float py = xb[NPTS + n];
    const float pz = xb[2 * NPTS + n];

    const float4* pA = (const float4*)(part + r * 2 * KNN);
    float arr[KNN];
#pragma unroll
    for (int k = 0; k < KNN; k += 4) {
        const float4 v = pA[k >> 2];
        arr[k] = v.x; arr[k + 1] = v.y; arr[k + 2] = v.z; arr[k + 3] = v.w;
    }
#pragma unroll
    for (int k = 0; k < KNN; k += 4) {
        const float4 v = pA[(KNN + k) >> 2];
        insert_t(arr, v.x); insert_t(arr, v.y); insert_t(arr, v.z); insert_t(arr, v.w);
    }
    finalize_row(arr, px, py, pz, r, lane, kmaxA, kminA, acc);
}

// ---- fallback K1 (round-1, verified): single block per 64 rows ----
__global__ __launch_bounds__(BLK, 8) void knn_kernel(
    const float* __restrict__ x, const float4* __restrict__ tile4,
    float* __restrict__ kmaxA, float* __restrict__ kminA, float* __restrict__ acc)
{
    __shared__ float shmem[(WPB - 1) * 64 * LSTR];
    __shared__ unsigned threshS[64];

    const int tid  = threadIdx.x;
    const int lane = tid & 63;
    const int wave = __builtin_amdgcn_readfirstlane(tid >> 6);
    const int rowBase = blockIdx.x * 64;
    const int row  = rowBase + lane;
    const int b    = rowBase >> 13;
    const int n    = row & (NPTS - 1);
    const float* xb = x + b * 3 * NPTS;

    const float px = xb[n];
    const float py = xb[NPTS + n];
    const float pz = xb[2 * NPTS + n];

    if (tid < 64) threshS[tid] = enc_f(NEG_INF);

    float arr[KNN];
#pragma unroll
    for (int j = 0; j < KNN; ++j) arr[j] = NEG_INF;

    float* bufw = shmem + wave * (CAP * 64);
    int cnt = 0;
    __syncthreads();

    const float4* __restrict__ tp = tile4 + b * NPTS + wave * SLICE;
    float th = NEG_INF;
    for (int c = 0; c < SLICE / 32; ++c) {
        th = dec_f(*(volatile unsigned*)(threshS + lane));
        const float4* tq = tp + c * 32;
        for (int g = 0; g < 8; ++g) {
#pragma unroll
            for (int u = 0; u < 4; ++u) {
                const float4 q = tq[g * 4 + u];
                const float t = fmaf(q.x, px, fmaf(q.y, py, fmaf(q.z, pz, q.w)));
                if (t > th) { bufw[cnt * 64 + lane] = t; ++cnt; }
            }
            if (__any(cnt > CAP - 4)) {
                flush_buf(arr, cnt, bufw, lane, threshS);
                th = dec_f(*(volatile unsigned*)(threshS + lane));
            }
        }
    }
    if (__any(cnt > 0)) flush_buf(arr, cnt, bufw, lane, threshS);
    __syncthreads();

    if (wave > 0) {
        float* dst = shmem + ((wave - 1) * 64 + lane) * LSTR;
#pragma unroll
        for (int j = 0; j < KNN; ++j) dst[j] = arr[j];
    }
    __syncthreads();

    if (wave == 0) {
        for (int wsrc = 0; wsrc < WPB - 1; ++wsrc) {
            const float* src = shmem + (wsrc * 64 + lane) * LSTR;
#pragma unroll
            for (int k = 0; k < KNN; ++k) insert_t(arr, src[k]);
        }
        finalize_row(arr, px, py, pz, row, lane, kmaxA, kminA, acc);
    }
}

// K1 (fallback, LDS tile): used only if ws_size can't hold the tile.
__global__ __launch_bounds__(BLK) void knn_kernel_lds(
    const float* __restrict__ x,
    float* __restrict__ kmaxA, float* __restrict__ kminA, float* __restrict__ acc)
{
    __shared__ float4 tile[2048];
    __shared__ float  lists[(WPB - 1) * 64 * LSTR];

    const int tid  = threadIdx.x;
    const int lane = tid & 63;
    const int wave = tid >> 6;
    const int rowBase = blockIdx.x * 64;
    const int row  = rowBase + lane;
    const int b    = rowBase >> 13;
    const int n    = row & (NPTS - 1);
    const float* xb = x + b * 3 * NPTS;

    const float px = xb[n];
    const float py = xb[NPTS + n];
    const float pz = xb[2 * NPTS + n];

    float arr[KNN];
#pragma unroll
    for (int j = 0; j < KNN; ++j) arr[j] = NEG_INF;

    for (int t0 = 0; t0 < NPTS; t0 += 2048) {
        __syncthreads();
        const int i4 = tid * 4;
        const float4 qx4 = *(const float4*)(xb + t0 + i4);
        const float4 qy4 = *(const float4*)(xb + NPTS + t0 + i4);
        const float4 qz4 = *(const float4*)(xb + 2 * NPTS + t0 + i4);
        tile[i4 + 0] = make_float4(qx4.x, qy4.x, qz4.x, -0.5f * (qx4.x*qx4.x + qy4.x*qy4.x + qz4.x*qz4.x));
        tile[i4 + 1] = make_float4(qx4.y, qy4.y, qz4.y, -0.5f * (qx4.y*qx4.y + qy4.y*qy4.y + qz4.y*qz4.y));
        tile[i4 + 2] = make_float4(qx4.z, qy4.z, qz4.z, -0.5f * (qx4.z*qx4.z + qy4.z*qy4.z + qz4.z*qz4.z));
        tile[i4 + 3] = make_float4(qx4.w, qy4.w, qz4.w, -0.5f * (qx4.w*qx4.w + qy4.w*qy4.w + qz4.w*qz4.w));
        __syncthreads();
        const float4* base = tile + wave * 256;
#pragma unroll 4
        for (int i = 0; i < 256; ++i) {
            const float4 q = base[i];
            float t = fmaf(q.x, px, fmaf(q.y, py, fmaf(q.z, pz, q.w)));
            insert_t(arr, t);
        }
    }
    __syncthreads();

    if (wave > 0) {
        float* dst = lists + ((wave - 1) * 64 + lane) * LSTR;
#pragma unroll
        for (int j = 0; j < KNN; ++j) dst[j] = arr[j];
    }
    __syncthreads();

    if (wave == 0) {
        for (int wsrc = 0; wsrc < WPB - 1; ++wsrc) {
            const float* src = lists + (wsrc * 64 + lane) * LSTR;
#pragma unroll
            for (int k = 0; k < KNN; ++k) insert_t(arr, src[k]);
        }
        finalize_row(arr, px, py, pz, row, lane, kmaxA, kminA, acc);
    }
}

// K2: per-thread BN-coefficient computation (16 rsqrt, trivial) + output.
// out[b,c,n] = lrelu(a_c * (a_c>=0 ? kmax : kmin) + d_c)
__global__ __launch_bounds__(256) void out_kernel(
    const float* __restrict__ kmaxA, const float* __restrict__ kminA,
    const float* __restrict__ acc,
    const float* __restrict__ w, const float* __restrict__ gamma,
    const float* __restrict__ beta, float* __restrict__ out)
{
    const int r = blockIdx.x * 256 + threadIdx.x;   // 0..32767
    const int b = r >> 13;
    const int n = r & (NPTS - 1);
    const float mu  = acc[0] * (1.0f / MTOTF);
    float var = acc[1] * (1.0f / MTOTF) - mu * mu;
    var = fmaxf(var, 0.f);
    const float kmax = kmaxA[r];
    const float kmin = kminA[r];
#pragma unroll
    for (int c = 0; c < 16; ++c) {
        const float wc = w[c];
        const float a = gamma[c] * wc * rsqrtf(wc * wc * var + 1e-5f);
        const float d = beta[c] - a * mu;     // conv bias cancels inside BN
        float v = a * (a >= 0.f ? kmax : kmin) + d;
        v = (v >= 0.f) ? v : 0.2f * v;
        out[(b * 16 + c) * NPTS + n] = v;
    }
}

extern "C" void kernel_launch(void* const* d_in, const int* in_sizes, int n_in,
                              void* d_out, int out_size, void* d_ws, size_t ws_size,
                              hipStream_t stream)
{
    const float* x     = (const float*)d_in[0];
    const float* w     = (const float*)d_in[1];
    const float* gamma = (const float*)d_in[3];
    const float* beta  = (const float*)d_in[4];
    float* out = (float*)d_out;
    float* ws  = (float*)d_ws;

    float* kmaxA = ws;                       // NROWS floats
    float* kminA = ws + NROWS;               // NROWS floats
    float* acc   = ws + 2 * NROWS;           // 2 floats
    // tile at 16B-aligned float offset 2*NROWS+4
    float4* tile4 = (float4*)(ws + 2 * NROWS + 4);
    float* part = ws + (2 * NROWS + 4) + 4 * NROWS;   // 32768*40 floats, 16B-aligned
    const size_t need_tile  = (size_t)(2 * NROWS + 4) * 4 + (size_t)NROWS * 16;
    const size_t need_split = need_tile + (size_t)NROWS * 2 * KNN * 4;

    if (ws_size >= need_split) {
        prep_kernel<<<NROWS / 256, 256, 0, stream>>>(x, tile4, acc);
        knn_hot_kernel<<<2 * (NROWS / 64), BLK, 0, stream>>>(x, tile4, part);
        merge_kernel<<<NROWS / 256, 256, 0, stream>>>(x, part, kmaxA, kminA, acc);
    } else if (ws_size >= need_tile) {
        prep_kernel<<<NROWS / 256, 256, 0, stream>>>(x, tile4, acc);
        knn_kernel<<<NROWS / 64, BLK, 0, stream>>>(x, tile4, kmaxA, kminA, acc);
    } else {
        prep_kernel<<<1, 256, 0, stream>>>(x, tile4, acc);      // only zeroes acc
        knn_kernel_lds<<<NROWS / 64, BLK, 0, stream>>>(x, kmaxA, kminA, acc);
    }
    out_kernel<<<NROWS / 256, 256, 0, stream>>>(kmaxA, kminA, acc, w, gamma, beta, out);
}

// Round 4
// 212.605 us; speedup vs baseline: 2.0155x; 2.0155x over previous
//
#include <hip/hip_runtime.h>
#include <stdint.h>

#define NPTS  8192
#define NB    4
#define KNN   20
#define NROWS (NB * NPTS)        // 32768
#define MTOTF 655360.0f          // NROWS * KNN
#define WPB   8                  // waves per block; all waves share the same 64 rows
#define BLK   (WPB * 64)         // 512 threads
#define SLICE (NPTS / WPB)       // 1024 candidates per wave (fallback kernel)
#define HALF  (NPTS / 2)         // 4096 candidates per split block
#define SLICE2 (HALF / WPB)      // 512 candidates per wave -> 256 pairs
#define LSTR  (KNN + 1)          // stride-21: odd stride -> conflict-free lists
#define CAP   12                 // fallback push-buffer slots
#define CW2   8                  // pair-slots per (wave,lane) section (8 pairs = 16 values)
#define PWARM 16                 // warm-up pairs per wave (32 candidates)
#define PPH   16                 // pairs per phase (32 candidates)
#define NPH2  ((SLICE2 / 2 - PWARM) / PPH)   // 15 scan phases
#define NEG_INF -3.0e38f

typedef float f32x2 __attribute__((ext_vector_type(2)));

__device__ __forceinline__ float med3f(float a, float b, float c) {
    return __builtin_amdgcn_fmed3f(a, b, c);
}

// packed fma: <2 x float> fma -> v_pk_fma_f32 on gfx950 (worst case: 2 v_fma)
__device__ __forceinline__ f32x2 fma2(f32x2 a, f32x2 b, f32x2 c) {
#if __has_builtin(__builtin_elementwise_fma)
    return __builtin_elementwise_fma(a, b, c);
#else
    f32x2 r; r.x = fmaf(a.x, b.x, c.x); r.y = fmaf(a.y, b.y, c.y); return r;
#endif
}

// Monotone float<->uint encoding so LDS atomicMax works as float-max (any sign).
__device__ __forceinline__ unsigned enc_f(float f) {
    unsigned u = __float_as_uint(f);
    return (u & 0x80000000u) ? ~u : (u | 0x80000000u);
}
__device__ __forceinline__ float dec_f(unsigned u) {
    return __uint_as_float((u & 0x80000000u) ? (u & 0x7fffffffu) : ~u);
}

// Insert t into descending top-KNN list (arr[0] = largest t = nearest point).
// Dropping off the bottom is always exact: 20 larger witnesses exist.
__device__ __forceinline__ void insert_t(float arr[KNN], float t) {
#pragma unroll
    for (int j = KNN - 1; j > 0; --j) arr[j] = med3f(t, arr[j - 1], arr[j]);
    arr[0] = fmaxf(arr[0], t);
}

// ---- fallback (round-1) flush: fixed CAP, padded ----
__device__ __forceinline__ void flush_buf(float arr[KNN], int& cnt,
    const float* bufw, int lane, unsigned* threshS) {
#pragma unroll
    for (int s = 0; s < CAP; ++s) {
        const float v = bufw[s * 64 + lane];
        insert_t(arr, (s < cnt) ? v : NEG_INF);
    }
    cnt = 0;
    atomicMax(&threshS[lane], enc_f(arr[KNN - 1]));
}

// ---- pair flush: chunk-skippable (2 pair-slots = 4 values per uniform test).
// Junk components (below-threshold pair partners) are rejected by the ladder
// bottom exactly; each wave drains its OWN section into its OWN register
// ladder -> fully parallel across waves (round-3 lesson: never serialize this).
__device__ __forceinline__ void flush_pairs(float arr[KNN], int& cnt,
    const f32x2* secp, int lane, unsigned* threshS) {
#pragma unroll
    for (int s0 = 0; s0 < CW2; s0 += 2) {
        if (__any(cnt > s0)) {
#pragma unroll
            for (int s = s0; s < s0 + 2; ++s) {
                const f32x2 v = secp[s * 64];
                const bool a = (s < cnt);
                insert_t(arr, a ? v.x : NEG_INF);
                insert_t(arr, a ? v.y : NEG_INF);
            }
        }
    }
    cnt = 0;
    atomicMax(&threshS[lane], enc_f(arr[KNN - 1]));
}

// Shared tail: caller holds the merged descending-t list for row `row`.
// t = p.q - |q|^2/2, d2 = |p|^2 - 2t  (arr[0] = largest t = nearest).
__device__ __forceinline__ void finalize_row(
    float arr[KNN], float px, float py, float pz, int row, int lane,
    float* __restrict__ kmaxA, float* __restrict__ kminA, float* __restrict__ acc)
{
    const float pn2 = px * px + py * py + pz * pz;
    float sum = 0.f, sum2 = 0.f, dmin = 0.f, dmax = 0.f;
#pragma unroll
    for (int k = 0; k < KNN; ++k) {
        float d2 = fmaxf(fmaf(-2.f, arr[k], pn2), 0.f);
        float d = sqrtf(d2);
        sum += d; sum2 += d2;
        if (k == 0) dmin = d;
        dmax = d;
    }
    kmaxA[row] = dmax;
    kminA[row] = dmin;
#pragma unroll
    for (int o = 32; o; o >>= 1) {
        sum  += __shfl_down(sum,  o, 64);
        sum2 += __shfl_down(sum2, o, 64);
    }
    if (lane == 0) { atomicAdd(acc, sum); atomicAdd(acc + 1, sum2); }
}

// Prep (old layout, for fallback path): tile4[i] = (qx,qy,qz,-|q|^2/2).
__global__ __launch_bounds__(256) void prep_kernel(
    const float* __restrict__ x, float4* __restrict__ tile4, float* __restrict__ acc)
{
    const int i = blockIdx.x * 256 + threadIdx.x;    // 0..32767
    const int b = i >> 13;
    const int m = i & (NPTS - 1);
    const float* xb = x + b * 3 * NPTS;
    const float qx = xb[m], qy = xb[NPTS + m], qz = xb[2 * NPTS + m];
    tile4[i] = make_float4(qx, qy, qz, -0.5f * (qx * qx + qy * qy + qz * qz));
    if (i < 2) acc[i] = 0.f;
}

// Prep (pair layout, main path): for candidate pair (2j, 2j+1):
// tile4[2p] = (x0,x1,y0,y1), tile4[2p+1] = (z0,z1,w0,w1), w = -|q|^2/2.
// f32x2 views of this are the direct v_pk_fma operands.
__global__ __launch_bounds__(256) void prep_pair_kernel(
    const float* __restrict__ x, float4* __restrict__ tile4, float* __restrict__ acc)
{
    const int p = blockIdx.x * 256 + threadIdx.x;    // 0..16383 (pair index)
    const int b = p >> 12;
    const int j = p & (NPTS / 2 - 1);
    const float* xb = x + b * 3 * NPTS;
    const f32x2 xx = *(const f32x2*)(xb + 2 * j);
    const f32x2 yy = *(const f32x2*)(xb + NPTS + 2 * j);
    const f32x2 zz = *(const f32x2*)(xb + 2 * NPTS + 2 * j);
    const float w0 = -0.5f * (xx.x * xx.x + yy.x * yy.x + zz.x * zz.x);
    const float w1 = -0.5f * (xx.y * xx.y + yy.y * yy.y + zz.y * zz.y);
    tile4[2 * p + 0] = make_float4(xx.x, xx.y, yy.x, yy.y);
    tile4[2 * p + 1] = make_float4(zz.x, zz.y, w0, w1);
    if (p < 2) acc[p] = 0.f;
}

// K1 (main): round-2 structure (per-wave register ladders + shared threshold,
// NO barriers in the scan) with a packed-pair inner loop:
//   3 v_pk_fma (2 cands) + v_max + v_cmp + cnt/addr + rare ds_write_b64.
// Tail: 3-step pairwise tree merge instead of serial 7-list merge.
__global__ __launch_bounds__(BLK, 8) void knn_pk_kernel(
    const float* __restrict__ x, const float4* __restrict__ tile4,
    float* __restrict__ part)
{
    // Aliased LDS: pair sections (8*8*64*8B = 32768B) during the scan,
    // tree-merge lists (4*64*21*4B = 21504B) after the drain barrier.
    __shared__ __align__(16) char smem[WPB * CW2 * 64 * sizeof(f32x2)];
    __shared__ unsigned threshS[64];
    f32x2* hot = (f32x2*)smem;
    float* ml  = (float*)smem;

    const int tid  = threadIdx.x;
    const int lane = tid & 63;
    const int wave = __builtin_amdgcn_readfirstlane(tid >> 6);
    const int rb   = blockIdx.x >> 1;        // row-group 0..511
    const int half = blockIdx.x & 1;         // candidate half
    const int rowBase = rb * 64;
    const int row  = rowBase + lane;
    const int b    = rowBase >> 13;
    const int n    = row & (NPTS - 1);
    const float* xb = x + b * 3 * NPTS;
    const float px = xb[n];
    const float py = xb[NPTS + n];
    const float pz = xb[2 * NPTS + n];
    const f32x2 px2 = {px, px}, py2 = {py, py}, pz2 = {pz, pz};

    if (tid < 64) threshS[tid] = enc_f(NEG_INF);

    float arr[KNN];
#pragma unroll
    for (int j = 0; j < KNN; ++j) arr[j] = NEG_INF;
    __syncthreads();

    // pair pointer: 4 consecutive f32x2 per pair (x01,y01,z01,w01)
    const f32x2* __restrict__ q2 = (const f32x2*)tile4;
    const int pbase = b * (NPTS / 2) + half * (HALF / 2) + wave * (SLICE2 / 2);

    // Warm-up: private ladder over first 16 pairs; publish real 20-of-32.
#pragma unroll 4
    for (int i = 0; i < PWARM; ++i) {
        const f32x2* tq = q2 + 4 * (pbase + i);
        const f32x2 r = fma2(tq[0], px2, fma2(tq[1], py2, fma2(tq[2], pz2, tq[3])));
        insert_t(arr, r.x);
        insert_t(arr, r.y);
    }
    atomicMax(&threshS[lane], enc_f(arr[KNN - 1]));

    f32x2* secp = hot + (wave * CW2) * 64 + lane;
    int cnt = 0;

    for (int p = 0; p < NPH2; ++p) {
        // refresh shared threshold once per phase (stale = conservative)
        float th = dec_f(*(volatile unsigned*)(threshS + lane));
        const f32x2* tq = q2 + 4 * (pbase + PWARM + p * PPH);
        for (int g = 0; g < 4; ++g) {
#pragma unroll
            for (int u = 0; u < 4; ++u) {
                const int j = g * 4 + u;
                const f32x2 ax = tq[4 * j + 0];      // wave-uniform -> scalar load
                const f32x2 ay = tq[4 * j + 1];
                const f32x2 az = tq[4 * j + 2];
                const f32x2 aw = tq[4 * j + 3];
                const f32x2 r = fma2(ax, px2, fma2(ay, py2, fma2(az, pz2, aw)));
                secp[cnt * 64] = r;                  // always-store pair (b64)
                cnt += (fmaxf(r.x, r.y) > th);       // keep pair if max beats th
            }
            // entering a group with cnt<=CW2-4 keeps stores in-bounds
            if (__any(cnt > CW2 - 4)) {
                flush_pairs(arr, cnt, secp, lane, threshS);
                th = dec_f(*(volatile unsigned*)(threshS + lane));
            }
        }
    }
    if (__any(cnt > 0)) flush_pairs(arr, cnt, secp, lane, threshS);
    __syncthreads();   // all section use done before aliased list writes

    // Tree merge: (0<-1)(2<-3)(4<-5)(6<-7) -> (0<-2)(4<-6) -> (0<-4)
    if (wave & 1) {
        float* d = ml + (wave >> 1) * (64 * LSTR) + lane * LSTR;
#pragma unroll
        for (int k = 0; k < KNN; ++k) d[k] = arr[k];
    }
    __syncthreads();
    if (!(wave & 1)) {
        const float* s = ml + (wave >> 1) * (64 * LSTR) + lane * LSTR;
#pragma unroll
        for (int k = 0; k < KNN; ++k) insert_t(arr, s[k]);
    }
    __syncthreads();
    if (!(wave & 1) && (wave & 2)) {
        float* d = ml + (wave >> 2) * (64 * LSTR) + lane * LSTR;
#pragma unroll
        for (int k = 0; k < KNN; ++k) d[k] = arr[k];
    }
    __syncthreads();
    if ((wave & 3) == 0) {
        const float* s = ml + (wave >> 2) * (64 * LSTR) + lane * LSTR;
#pragma unroll
        for (int k = 0; k < KNN; ++k) insert_t(arr, s[k]);
    }
    __syncthreads();
    if (wave == 4) {
        float* d = ml + lane * LSTR;
#pragma unroll
        for (int k = 0; k < KNN; ++k) d[k] = arr[k];
    }
    __syncthreads();
    if (wave == 0) {
        const float* s = ml + lane * LSTR;
#pragma unroll
        for (int k = 0; k < KNN; ++k) insert_t(arr, s[k]);
        // write sorted partial list: part[(row*2+half)*20 .. +19]
        float4* dst = (float4*)(part + (row * 2 + half) * KNN);
#pragma unroll
        for (int k = 0; k < KNN; k += 4)
            dst[k >> 2] = make_float4(arr[k], arr[k + 1], arr[k + 2], arr[k + 3]);
    }
}

// K1b: merge the two sorted partial lists per row, then finalize
// (kmax/kmin + BN-stat atomics). One thread per row.
__global__ __launch_bounds__(256) void merge_kernel(
    const float* __restrict__ x, const float* __restrict__ part,
    float* __restrict__ kmaxA, float* __restrict__ kminA, float* __restrict__ acc)
{
    const int r = blockIdx.x * 256 + threadIdx.x;   // 0..32767
    const int lane = threadIdx.x & 63;
    const int b = r >> 13;
    const int n = r & (NPTS - 1);
    const float* xb = x + b * 3 * NPTS;
    const float px = xb[n];
    const float py = xb[NPTS + n];
    const float pz = xb[2 * NPTS + n];

    const float4* pA = (const float4*)(part + r * 2 * KNN);
    float arr[KNN];
#pragma unroll
    for (int k = 0; k < KNN; k += 4) {
        const float4 v = pA[k >> 2];
        arr[k] = v.x; arr[k + 1] = v.y; arr[k + 2] = v.z; arr[k + 3] = v.w;
    }
#pragma unroll
    for (int k = 0; k < KNN; k += 4) {
        const float4 v = pA[(KNN + k) >> 2];
        insert_t(arr, v.x); insert_t(arr, v.y); insert_t(arr, v.z); insert_t(arr, v.w);
    }
    finalize_row(arr, px, py, pz, r, lane, kmaxA, kminA, acc);
}

// ---- fallback K1 (round-1, verified): single block per 64 rows, old tile ----
__global__ __launch_bounds__(BLK, 8) void knn_kernel(
    const float* __restrict__ x, const float4* __restrict__ tile4,
    float* __restrict__ kmaxA, float* __restrict__ kminA, float* __restrict__ acc)
{
    __shared__ float shmem[(WPB - 1) * 64 * LSTR];
    __shared__ unsigned threshS[64];

    const int tid  = threadIdx.x;
    const int lane = tid & 63;
    const int wave = __builtin_amdgcn_readfirstlane(tid >> 6);
    const int rowBase = blockIdx.x * 64;
    const int row  = rowBase + lane;
    const int b    = rowBase >> 13;
    const int n    = row & (NPTS - 1);
    const float* xb = x + b * 3 * NPTS;

    const float px = xb[n];
    const float py = xb[NPTS + n];
    const float pz = xb[2 * NPTS + n];

    if (tid < 64) threshS[tid] = enc_f(NEG_INF);

    float arr[KNN];
#pragma unroll
    for (int j = 0; j < KNN; ++j) arr[j] = NEG_INF;

    float* bufw = shmem + wave * (CAP * 64);
    int cnt = 0;
    __syncthreads();

    const float4* __restrict__ tp = tile4 + b * NPTS + wave * SLICE;
    float th = NEG_INF;
    for (int c = 0; c < SLICE / 32; ++c) {
        th = dec_f(*(volatile unsigned*)(threshS + lane));
        const float4* tq = tp + c * 32;
        for (int g = 0; g < 8; ++g) {
#pragma unroll
            for (int u = 0; u < 4; ++u) {
                const float4 q = tq[g * 4 + u];
                const float t = fmaf(q.x, px, fmaf(q.y, py, fmaf(q.z, pz, q.w)));
                if (t > th) { bufw[cnt * 64 + lane] = t; ++cnt; }
            }
            if (__any(cnt > CAP - 4)) {
                flush_buf(arr, cnt, bufw, lane, threshS);
                th = dec_f(*(volatile unsigned*)(threshS + lane));
            }
        }
    }
    if (__any(cnt > 0)) flush_buf(arr, cnt, bufw, lane, threshS);
    __syncthreads();

    if (wave > 0) {
        float* dst = shmem + ((wave - 1) * 64 + lane) * LSTR;
#pragma unroll
        for (int j = 0; j < KNN; ++j) dst[j] = arr[j];
    }
    __syncthreads();

    if (wave == 0) {
        for (int wsrc = 0; wsrc < WPB - 1; ++wsrc) {
            const float* src = shmem + (wsrc * 64 + lane) * LSTR;
#pragma unroll
            for (int k = 0; k < KNN; ++k) insert_t(arr, src[k]);
        }
        finalize_row(arr, px, py, pz, row, lane, kmaxA, kminA, acc);
    }
}

// K1 (fallback, LDS tile): used only if ws_size can't hold the tile.
__global__ __launch_bounds__(BLK) void knn_kernel_lds(
    const float* __restrict__ x,
    float* __restrict__ kmaxA, float* __restrict__ kminA, float* __restrict__ acc)
{
    __shared__ float4 tile[2048];
    __shared__ float  lists[(WPB - 1) * 64 * LSTR];

    const int tid  = threadIdx.x;
    const int lane = tid & 63;
    const int wave = tid >> 6;
    const int rowBase = blockIdx.x * 64;
    const int row  = rowBase + lane;
    const int b    = rowBase >> 13;
    const int n    = row & (NPTS - 1);
    const float* xb = x + b * 3 * NPTS;

    const float px = xb[n];
    const float py = xb[NPTS + n];
    const float pz = xb[2 * NPTS + n];

    float arr[KNN];
#pragma unroll
    for (int j = 0; j < KNN; ++j) arr[j] = NEG_INF;

    for (int t0 = 0; t0 < NPTS; t0 += 2048) {
        __syncthreads();
        const int i4 = tid * 4;
        const float4 qx4 = *(const float4*)(xb + t0 + i4);
        const float4 qy4 = *(const float4*)(xb + NPTS + t0 + i4);
        const float4 qz4 = *(const float4*)(xb + 2 * NPTS + t0 + i4);
        tile[i4 + 0] = make_float4(qx4.x, qy4.x, qz4.x, -0.5f * (qx4.x*qx4.x + qy4.x*qy4.x + qz4.x*qz4.x));
        tile[i4 + 1] = make_float4(qx4.y, qy4.y, qz4.y, -0.5f * (qx4.y*qx4.y + qy4.y*qy4.y + qz4.y*qz4.y));
        tile[i4 + 2] = make_float4(qx4.z, qy4.z, qz4.z, -0.5f * (qx4.z*qx4.z + qy4.z*qy4.z + qz4.z*qz4.z));
        tile[i4 + 3] = make_float4(qx4.w, qy4.w, qz4.w, -0.5f * (qx4.w*qx4.w + qy4.w*qy4.w + qz4.w*qz4.w));
        __syncthreads();
        const float4* base = tile + wave * 256;
#pragma unroll 4
        for (int i = 0; i < 256; ++i) {
            const float4 q = base[i];
            float t = fmaf(q.x, px, fmaf(q.y, py, fmaf(q.z, pz, q.w)));
            insert_t(arr, t);
        }
    }
    __syncthreads();

    if (wave > 0) {
        float* dst = lists + ((wave - 1) * 64 + lane) * LSTR;
#pragma unroll
        for (int j = 0; j < KNN; ++j) dst[j] = arr[j];
    }
    __syncthreads();

    if (wave == 0) {
        for (int wsrc = 0; wsrc < WPB - 1; ++wsrc) {
            const float* src = lists + (wsrc * 64 + lane) * LSTR;
#pragma unroll
            for (int k = 0; k < KNN; ++k) insert_t(arr, src[k]);
        }
        finalize_row(arr, px, py, pz, row, lane, kmaxA, kminA, acc);
    }
}

// K2: per-thread BN-coefficient computation (16 rsqrt, trivial) + output.
// out[b,c,n] = lrelu(a_c * (a_c>=0 ? kmax : kmin) + d_c)
__global__ __launch_bounds__(256) void out_kernel(
    const float* __restrict__ kmaxA, const float* __restrict__ kminA,
    const float* __restrict__ acc,
    const float* __restrict__ w, const float* __restrict__ gamma,
    const float* __restrict__ beta, float* __restrict__ out)
{
    const int r = blockIdx.x * 256 + threadIdx.x;   // 0..32767
    const int b = r >> 13;
    const int n = r & (NPTS - 1);
    const float mu  = acc[0] * (1.0f / MTOTF);
    float var = acc[1] * (1.0f / MTOTF) - mu * mu;
    var = fmaxf(var, 0.f);
    const float kmax = kmaxA[r];
    const float kmin = kminA[r];
#pragma unroll
    for (int c = 0; c < 16; ++c) {
        const float wc = w[c];
        const float a = gamma[c] * wc * rsqrtf(wc * wc * var + 1e-5f);
        const float d = beta[c] - a * mu;     // conv bias cancels inside BN
        float v = a * (a >= 0.f ? kmax : kmin) + d;
        v = (v >= 0.f) ? v : 0.2f * v;
        out[(b * 16 + c) * NPTS + n] = v;
    }
}

extern "C" void kernel_launch(void* const* d_in, const int* in_sizes, int n_in,
                              void* d_out, int out_size, void* d_ws, size_t ws_size,
                              hipStream_t stream)
{
    const float* x     = (const float*)d_in[0];
    const float* w     = (const float*)d_in[1];
    const float* gamma = (const float*)d_in[3];
    const float* beta  = (const float*)d_in[4];
    float* out = (float*)d_out;
    float* ws  = (float*)d_ws;

    float* kmaxA = ws;                       // NROWS floats
    float* kminA = ws + NROWS;               // NROWS floats
    float* acc   = ws + 2 * NROWS;           // 2 floats
    // tile at 16B-aligned float offset 2*NROWS+4
    float4* tile4 = (float4*)(ws + 2 * NROWS + 4);
    float* part = ws + (2 * NROWS + 4) + 4 * NROWS;   // 32768*40 floats, 16B-aligned
    const size_t need_tile  = (size_t)(2 * NROWS + 4) * 4 + (size_t)NROWS * 16;
    const size_t need_split = need_tile + (size_t)NROWS * 2 * KNN * 4;

    if (ws_size >= need_split) {
        prep_pair_kernel<<<NROWS / 512, 256, 0, stream>>>(x, tile4, acc);
        knn_pk_kernel<<<2 * (NROWS / 64), BLK, 0, stream>>>(x, tile4, part);
        merge_kernel<<<NROWS / 256, 256, 0, stream>>>(x, part, kmaxA, kminA, acc);
    } else if (ws_size >= need_tile) {
        prep_kernel<<<NROWS / 256, 256, 0, stream>>>(x, tile4, acc);
        knn_kernel<<<NROWS / 64, BLK, 0, stream>>>(x, tile4, kmaxA, kminA, acc);
    } else {
        prep_kernel<<<1, 256, 0, stream>>>(x, tile4, acc);      // only zeroes acc
        knn_kernel_lds<<<NROWS / 64, BLK, 0, stream>>>(x, kmaxA, kminA, acc);
    }
    out_kernel<<<NROWS / 256, 256, 0, stream>>>(kmaxA, kminA, acc, w, gamma, beta, out);
}